// Round 6
// baseline (609.792 us; speedup 1.0000x reference)
//
#include <hip/hip_runtime.h>
#include <hip/hip_bf16.h>
#include <hip/hip_fp16.h>
#include <hip/hip_cooperative_groups.h>

namespace cg = cooperative_groups;

constexpr int IN_DIM = 128;
constexpr int HID    = 256;

typedef _Float16 f16x8 __attribute__((ext_vector_type(8)));
typedef float    f32x4 __attribute__((ext_vector_type(4)));

// ---- W panel conversion helper (fp32 [K,256] -> fp16 MFMA panel) ----
__device__ inline void conv_B_elem(const float* B, ushort* Bp, int id) {
    int k  = id >> 6;
    int n4 = (id & 63) * 4;
    float4 v = *(const float4*)(B + (size_t)k * 256 + n4);
    size_t base = (size_t)(k >> 5) * (256 * 32) + (k & 31);
    Bp[base + (size_t)(n4 + 0) * 32] = __half_as_ushort(__float2half(v.x));
    Bp[base + (size_t)(n4 + 1) * 32] = __half_as_ushort(__float2half(v.y));
    Bp[base + (size_t)(n4 + 2) * 32] = __half_as_ushort(__float2half(v.z));
    Bp[base + (size_t)(n4 + 3) * 32] = __half_as_ushort(__float2half(v.w));
}

// ---------------- ONE cooperative setup kernel -----------------------------
// Replaces {memset, convert_count, scan_partial, scan_rest, scatter_src}
// (5 dispatches) with a single dispatch + 4 grid.sync()s. Phases:
//  P0 zero deg
//  P1 convert W1/W2 panels + x->fp16, count degrees (rank = atomic return)
//  P2 per-256-chunk LDS scan partials + dinv
//  P3 block 0 scans the <=256 block sums -> bprefix (exclusive), rowptr[n]
//  P4 emit rowptr (for aggregates) + atomic-free scatter, with rowptr[d]
//     recomputed inline from escan+bprefix so no extra sync is needed.
__global__ __launch_bounds__(256, 4) void setup_coop(
    const float* __restrict__ W1, ushort* __restrict__ B1p,
    const float* __restrict__ W2, ushort* __restrict__ B2p,
    const float* __restrict__ x, ushort* __restrict__ xh, int total4,
    const int* __restrict__ src, const int* __restrict__ dst,
    ushort* __restrict__ rank, int* __restrict__ deg,
    int* __restrict__ escan, int* __restrict__ bsum,
    int* __restrict__ bprefix, int* __restrict__ rowptr,
    float* __restrict__ dinv, ushort* __restrict__ esrc,
    int n, int e, int nb)
{
    cg::grid_group grid = cg::this_grid();
    __shared__ int lds[256];
    int tid     = threadIdx.x;
    int gid0    = blockIdx.x * 256 + tid;
    int gstride = gridDim.x * 256;

    // P0: zero degree counters
    for (int i = gid0; i < n; i += gstride) deg[i] = 0;
    grid.sync();

    // P1: convert weights + features, count degrees with rank capture
    constexpr int C1 = IN_DIM * 64;
    constexpr int C2 = C1 + HID * 64;
    int citems = C2 + total4 + e;
    for (int id = gid0; id < citems; id += gstride) {
        if (id < C1) {
            conv_B_elem(W1, B1p, id);
        } else if (id < C2) {
            conv_B_elem(W2, B2p, id - C1);
        } else if (id < C2 + total4) {
            int i = id - C2;
            float4 v = *(const float4*)(x + (size_t)i * 4);
            ushort4 o;
            o.x = __half_as_ushort(__float2half(v.x));
            o.y = __half_as_ushort(__float2half(v.y));
            o.z = __half_as_ushort(__float2half(v.z));
            o.w = __half_as_ushort(__float2half(v.w));
            *(ushort4*)(xh + (size_t)i * 4) = o;
        } else {
            int i = id - (C2 + total4);
            rank[i] = (ushort)atomicAdd(&deg[dst[i]], 1);
        }
    }
    grid.sync();

    // P2: per-256-chunk inclusive scan -> escan (exclusive), bsum, dinv
    for (int lb = blockIdx.x; lb < nb; lb += gridDim.x) {
        int i = lb * 256 + tid;
        int v = (i < n) ? deg[i] : 0;
        if (i < n) dinv[i] = rsqrtf((float)v + 1.0f);
        lds[tid] = v;
        __syncthreads();
        for (int off = 1; off < 256; off <<= 1) {
            int a = lds[tid];
            int w = (tid >= off) ? lds[tid - off] : 0;
            __syncthreads();
            lds[tid] = a + w;
            __syncthreads();
        }
        if (i < n) escan[i] = lds[tid] - v;
        if (tid == 255) bsum[lb] = lds[255];
        __syncthreads();
    }
    grid.sync();

    // P3: scan the block sums (nb <= 256) -> bprefix (exclusive), rowptr[n]
    if (blockIdx.x == 0) {
        int v = (tid < nb) ? bsum[tid] : 0;
        lds[tid] = v;
        __syncthreads();
        for (int off = 1; off < 256; off <<= 1) {
            int a = lds[tid];
            int w = (tid >= off) ? lds[tid - off] : 0;
            __syncthreads();
            lds[tid] = a + w;
            __syncthreads();
        }
        bprefix[tid] = lds[tid] - v;
        if (tid == 0) rowptr[n] = lds[255];
    }
    grid.sync();

    // P4: rowptr for the aggregates + atomic-free scatter (inline rowptr[d])
    for (int i = gid0; i < n; i += gstride)
        rowptr[i] = escan[i] + bprefix[i >> 8];
    for (int i = gid0; i < e; i += gstride) {
        int d = dst[i];
        esrc[escan[d] + bprefix[d >> 8] + (int)rank[i]] = (ushort)src[i];
    }
}

// ---------------- aggregation: one wave per node, fp16 gather, 8-deep ------
// Proven round-0/3/4 structure: clean uint2 gathers, ushort edge stream,
// dinv[s] looked up from the L2-resident table, dinv[d] factored out.
template <int K>  // K halves per row: 128 or 256
__global__ __launch_bounds__(256) void aggregate_p(const ushort* __restrict__ h,
                                                   const int* __restrict__ rowptr,
                                                   const ushort* __restrict__ esrc,
                                                   const float* __restrict__ dinv,
                                                   ushort* __restrict__ Pp,
                                                   int n, int Mp) {
    constexpr int VH = K / 64;  // halves per lane: 2 or 4
    int wid  = (blockIdx.x * 256 + threadIdx.x) >> 6;
    int lane = threadIdx.x & 63;
    if (wid >= n) return;
    float di = dinv[wid];
    float acc[VH];
    {
        const ushort* row = h + (size_t)wid * K + lane * VH;
        if constexpr (VH == 4) {
            uint2 u = *(const uint2*)row;
            float2 fa = __half22float2(*(__half2*)&u.x);
            float2 fb = __half22float2(*(__half2*)&u.y);
            acc[0] = fa.x * di; acc[1] = fa.y * di; acc[2] = fb.x * di; acc[3] = fb.y * di;
        } else {
            uint u = *(const uint*)row;
            float2 fa = __half22float2(*(__half2*)&u);
            acc[0] = fa.x * di; acc[1] = fa.y * di;
        }
    }
    int beg = rowptr[wid], fin = rowptr[wid + 1];
    for (int b = beg; b < fin; b += 64) {
        int cnt = fin - b;
        if (cnt > 64) cnt = 64;
        int   sv = (lane < cnt) ? (int)esrc[b + lane] : 0;
        float wv = (lane < cnt) ? dinv[sv] : 0.f;
        int t = 0;
        for (; t + 8 <= cnt; t += 8) {
            float wr[8];
            if constexpr (VH == 4) {
                uint2 u[8];
#pragma unroll
                for (int k = 0; k < 8; k++) {
                    int s = __shfl(sv, t + k);
                    wr[k] = __shfl(wv, t + k);
                    u[k] = *(const uint2*)(h + (size_t)s * K + lane * VH);
                }
#pragma unroll
                for (int k = 0; k < 8; k++) {
                    float2 fa = __half22float2(*(__half2*)&u[k].x);
                    float2 fb = __half22float2(*(__half2*)&u[k].y);
                    acc[0] += fa.x * wr[k]; acc[1] += fa.y * wr[k];
                    acc[2] += fb.x * wr[k]; acc[3] += fb.y * wr[k];
                }
            } else {
                uint u[8];
#pragma unroll
                for (int k = 0; k < 8; k++) {
                    int s = __shfl(sv, t + k);
                    wr[k] = __shfl(wv, t + k);
                    u[k] = *(const uint*)(h + (size_t)s * K + lane * VH);
                }
#pragma unroll
                for (int k = 0; k < 8; k++) {
                    float2 fa = __half22float2(*(__half2*)&u[k]);
                    acc[0] += fa.x * wr[k]; acc[1] += fa.y * wr[k];
                }
            }
        }
        for (; t + 4 <= cnt; t += 4) {
            float wr[4];
            if constexpr (VH == 4) {
                uint2 u[4];
#pragma unroll
                for (int k = 0; k < 4; k++) {
                    int s = __shfl(sv, t + k);
                    wr[k] = __shfl(wv, t + k);
                    u[k] = *(const uint2*)(h + (size_t)s * K + lane * VH);
                }
#pragma unroll
                for (int k = 0; k < 4; k++) {
                    float2 fa = __half22float2(*(__half2*)&u[k].x);
                    float2 fb = __half22float2(*(__half2*)&u[k].y);
                    acc[0] += fa.x * wr[k]; acc[1] += fa.y * wr[k];
                    acc[2] += fb.x * wr[k]; acc[3] += fb.y * wr[k];
                }
            } else {
                uint u[4];
#pragma unroll
                for (int k = 0; k < 4; k++) {
                    int s = __shfl(sv, t + k);
                    wr[k] = __shfl(wv, t + k);
                    u[k] = *(const uint*)(h + (size_t)s * K + lane * VH);
                }
#pragma unroll
                for (int k = 0; k < 4; k++) {
                    float2 fa = __half22float2(*(__half2*)&u[k]);
                    acc[0] += fa.x * wr[k]; acc[1] += fa.y * wr[k];
                }
            }
        }
        for (; t < cnt; t++) {
            int   s = __shfl(sv, t);
            float w = __shfl(wv, t);
            const ushort* r = h + (size_t)s * K + lane * VH;
            if constexpr (VH == 4) {
                uint2 u = *(const uint2*)r;
                float2 fa = __half22float2(*(__half2*)&u.x);
                float2 fb = __half22float2(*(__half2*)&u.y);
                acc[0] += fa.x * w; acc[1] += fa.y * w;
                acc[2] += fb.x * w; acc[3] += fb.y * w;
            } else {
                uint u = *(const uint*)r;
                float2 fa = __half22float2(*(__half2*)&u);
                acc[0] += fa.x * w; acc[1] += fa.y * w;
            }
        }
    }
#pragma unroll
    for (int j = 0; j < VH; j++) acc[j] *= di;

    int kglob = lane * VH;
    int chunk = kglob >> 5;
    int inner = kglob & 31;
    size_t base = (size_t)chunk * Mp * 32 + (size_t)wid * 32 + inner;
    if constexpr (VH == 4) {
        __half2 p0 = __floats2half2_rn(acc[0], acc[1]);
        __half2 p1 = __floats2half2_rn(acc[2], acc[3]);
        *(uint2*)&Pp[base] = make_uint2(*(uint*)&p0, *(uint*)&p1);
    } else {
        __half2 p0 = __floats2half2_rn(acc[0], acc[1]);
        *(uint*)&Pp[base] = *(uint*)&p0;
    }
}

// ---------------- persistent-B fp16 MFMA GEMM ------------------------------
// MODE 1: C16[M,256] = fp16(relu(A@B + bias))
// MODE 2: out[M,2]  = relu(A@B + bias) @ Wl + bl
template <int K, int MODE>
__global__ __launch_bounds__(256, (MODE == 1) ? 2 : 1)
void gemm_p(const ushort* __restrict__ Ap, const ushort* __restrict__ Bp,
            const float* __restrict__ bias, ushort* __restrict__ C16,
            const float* __restrict__ Wl, const float* __restrict__ bl,
            float* __restrict__ out, int M, int Mp, int ntiles) {
    constexpr int NC   = K / 32;
    constexpr int NBUF = (MODE == 1) ? 2 : 1;
    __shared__ ushort Bsm[NC * 8192];          // whole B panel
    __shared__ ushort Asm[NBUF][NC * 1024];    // A tile(s) [chunk][row][32]

    int tid  = threadIdx.x;
    int w    = tid >> 6;
    int lane = tid & 63;
    int l15  = lane & 15;
    int quad = lane >> 4;

    for (int j = w; j < NC * 16; j += 4) {
        const ushort* g = Bp + (size_t)j * 512;
        __builtin_amdgcn_global_load_lds(
            (const __attribute__((address_space(1))) uint*)(g + (size_t)lane * 8),
            (__attribute__((address_space(3))) uint*)(Bsm + j * 512), 16, 0, 0);
    }

    auto stageA = [&](ushort* dl, int t) {
        int row0 = t * 32;
        for (int j = w; j < NC * 2; j += 4) {
            int c = j >> 1, sub = j & 1;
            const ushort* g = Ap + (size_t)c * Mp * 32 + (size_t)(row0 + sub * 16) * 32;
            __builtin_amdgcn_global_load_lds(
                (const __attribute__((address_space(1))) uint*)(g + (size_t)lane * 8),
                (__attribute__((address_space(3))) uint*)(dl + c * 1024 + sub * 512),
                16, 0, 0);
        }
    };

    float bj[4];
#pragma unroll
    for (int j = 0; j < 4; j++) bj[j] = bias[w * 64 + j * 16 + l15];
    float wl0[4], wl1[4];
    if constexpr (MODE == 2) {
#pragma unroll
        for (int j = 0; j < 4; j++) {
            int cj = w * 64 + j * 16 + l15;
            float2 wv = *(const float2*)(Wl + cj * 2);
            wl0[j] = wv.x; wl1[j] = wv.y;
        }
    }

    int cur = 0;
    if ((int)blockIdx.x < ntiles) stageA(Asm[0], blockIdx.x);

    for (int t = blockIdx.x; t < ntiles; t += gridDim.x) {
        __syncthreads();
        if constexpr (MODE == 1) {
            if (t + (int)gridDim.x < ntiles) stageA(Asm[cur ^ 1], t + gridDim.x);
        }
        f32x4 acc[2][4] = {};
#pragma unroll
        for (int c = 0; c < NC; c++) {
            f16x8 fa[2], fb[4];
#pragma unroll
            for (int i = 0; i < 2; i++) {
                int off = c * 1024 + (i * 16 + l15) * 32 + quad * 8;
                fa[i] = *(const f16x8*)&Asm[cur][off];
            }
#pragma unroll
            for (int j = 0; j < 4; j++) {
                int off = c * 8192 + (w * 64 + j * 16 + l15) * 32 + quad * 8;
                fb[j] = *(const f16x8*)&Bsm[off];
            }
#pragma unroll
            for (int i = 0; i < 2; i++)
#pragma unroll
                for (int j = 0; j < 4; j++)
                    acc[i][j] = __builtin_amdgcn_mfma_f32_16x16x32_f16(fa[i], fb[j], acc[i][j], 0, 0, 0);
        }

        int row0 = t * 32;
        if constexpr (MODE == 1) {
#pragma unroll
            for (int i = 0; i < 2; i++)
#pragma unroll
                for (int reg = 0; reg < 4; reg++) {
                    int r = row0 + i * 16 + quad * 4 + reg;
                    if (r < M) {
                        ushort* cp = C16 + (size_t)r * 256 + w * 64 + l15;
#pragma unroll
                        for (int j = 0; j < 4; j++) {
                            float v = fmaxf(acc[i][j][reg] + bj[j], 0.f);
                            cp[j * 16] = __half_as_ushort(__float2half(v));
                        }
                    }
                }
            cur ^= 1;
        } else {
            __shared__ float part[4][32][2];
#pragma unroll
            for (int i = 0; i < 2; i++)
#pragma unroll
                for (int reg = 0; reg < 4; reg++) {
                    float s0 = 0.f, s1 = 0.f;
#pragma unroll
                    for (int j = 0; j < 4; j++) {
                        float v = fmaxf(acc[i][j][reg] + bj[j], 0.f);
                        s0 += v * wl0[j];
                        s1 += v * wl1[j];
                    }
#pragma unroll
                    for (int off = 1; off < 16; off <<= 1) {
                        s0 += __shfl_xor(s0, off);
                        s1 += __shfl_xor(s1, off);
                    }
                    if (l15 == 0) {
                        int r = i * 16 + quad * 4 + reg;
                        part[w][r][0] = s0;
                        part[w][r][1] = s1;
                    }
                }
            __syncthreads();
            if (t + (int)gridDim.x < ntiles) stageA(Asm[0], t + gridDim.x);
            if (tid < 64) {
                int r = tid >> 1, o = tid & 1;
                int grr = row0 + r;
                if (grr < M) {
                    float s = part[0][r][o] + part[1][r][o] + part[2][r][o] + part[3][r][o] + bl[o];
                    out[(size_t)grr * 2 + o] = s;
                }
            }
        }
    }
}

// ---------------- launch ----------------

extern "C" void kernel_launch(void* const* d_in, const int* in_sizes, int n_in,
                              void* d_out, int out_size, void* d_ws, size_t ws_size,
                              hipStream_t stream) {
    const float* x  = (const float*)d_in[0];
    const int*   ei = (const int*)d_in[1];
    const float* W1 = (const float*)d_in[2];
    const float* b1 = (const float*)d_in[3];
    const float* W2 = (const float*)d_in[4];
    const float* b2 = (const float*)d_in[5];
    const float* Wl = (const float*)d_in[6];
    const float* bl = (const float*)d_in[7];
    float* out = (float*)d_out;

    int n = in_sizes[0] / IN_DIM;  // 50000
    int e = in_sizes[1] / 2;       // 600000
    const int* src = ei;
    const int* dst = ei + e;

    int gblocks = (n + 31) / 32;   // 32-row tiles
    int Mp = gblocks * 32;

    char* ws = (char*)d_ws;
    size_t off = 0;
    auto alloc = [&](size_t bytes) -> void* {
        void* p = ws + off;
        off += (bytes + 255) & ~(size_t)255;
        return p;
    };
    int*    deg     = (int*)alloc((size_t)n * 4);
    float*  dinv    = (float*)alloc((size_t)n * 4);
    int*    rowptr  = (int*)alloc((size_t)(n + 1) * 4);
    int*    escan   = (int*)alloc((size_t)n * 4);
    int*    bsum    = (int*)alloc(256 * 4);
    int*    bprefix = (int*)alloc(256 * 4);
    ushort* rank    = (ushort*)alloc((size_t)e * 2);
    ushort* esrc    = (ushort*)alloc((size_t)e * 2);
    ushort* xh      = (ushort*)alloc((size_t)n * IN_DIM * 2);
    ushort* h1      = (ushort*)alloc((size_t)n * HID * 2);
    ushort* A1p     = (ushort*)alloc((size_t)Mp * IN_DIM * 2);
    ushort* A2p     = (ushort*)alloc((size_t)Mp * HID * 2);
    ushort* B1p     = (ushort*)alloc((size_t)IN_DIM * 256 * 2);
    ushort* B2p     = (ushort*)alloc((size_t)HID * 256 * 2);

    int nb = (n + 255) / 256;   // 196 (<= 256 required by P3)
    int total4 = n * IN_DIM / 4;

    // one cooperative dispatch replaces the 5-kernel setup chain
    void* args[] = {
        (void*)&W1, (void*)&B1p, (void*)&W2, (void*)&B2p,
        (void*)&x,  (void*)&xh,  (void*)&total4,
        (void*)&src, (void*)&dst,
        (void*)&rank, (void*)&deg,
        (void*)&escan, (void*)&bsum, (void*)&bprefix, (void*)&rowptr,
        (void*)&dinv, (void*)&esrc,
        (void*)&n, (void*)&e, (void*)&nb
    };
    hipLaunchCooperativeKernel((void*)setup_coop, dim3(1024), dim3(256),
                               args, 0, stream);

    // layer 1: aggregate fp16 x -> A1 panel, persistent-B MFMA GEMM -> h1
    aggregate_p<IN_DIM><<<(n + 3) / 4, 256, 0, stream>>>(xh, rowptr, esrc, dinv,
                                                         A1p, n, Mp);
    gemm_p<IN_DIM, 1><<<512, 256, 0, stream>>>(A1p, B1p, b1, h1,
                                               nullptr, nullptr, nullptr,
                                               n, Mp, gblocks);

    // layer 2: aggregate fp16 h1 -> A2 panel, persistent-B GEMM + projection
    aggregate_p<HID><<<(n + 3) / 4, 256, 0, stream>>>(h1, rowptr, esrc, dinv,
                                                      A2p, n, Mp);
    gemm_p<HID, 2><<<256, 256, 0, stream>>>(A2p, B2p, b2, nullptr,
                                            Wl, bl, out, n, Mp, gblocks);
}

// Round 7
// 228.860 us; speedup vs baseline: 2.6645x; 2.6645x over previous
//
#include <hip/hip_runtime.h>
#include <hip/hip_bf16.h>
#include <hip/hip_fp16.h>

constexpr int IN_DIM = 128;
constexpr int HID    = 256;

typedef _Float16 f16x8 __attribute__((ext_vector_type(8)));
typedef float    f32x4 __attribute__((ext_vector_type(4)));

// ---- fused: W1/W2 -> fp16 panels, x -> fp16, count degrees + edge ranks ----
// rank[i] (ushort) = edge's arrival position at its destination (atomic
// return) -> the scatter needs NO atomics. Atomic latency hides under the
// streaming x->fp16 conversion.
__device__ inline void conv_B_elem(const float* B, ushort* Bp, int id) {
    int k  = id >> 6;
    int n4 = (id & 63) * 4;
    float4 v = *(const float4*)(B + (size_t)k * 256 + n4);
    size_t base = (size_t)(k >> 5) * (256 * 32) + (k & 31);
    Bp[base + (size_t)(n4 + 0) * 32] = __half_as_ushort(__float2half(v.x));
    Bp[base + (size_t)(n4 + 1) * 32] = __half_as_ushort(__float2half(v.y));
    Bp[base + (size_t)(n4 + 2) * 32] = __half_as_ushort(__float2half(v.z));
    Bp[base + (size_t)(n4 + 3) * 32] = __half_as_ushort(__float2half(v.w));
}

__global__ void convert_count(const float* __restrict__ W1, ushort* __restrict__ B1p,
                              const float* __restrict__ W2, ushort* __restrict__ B2p,
                              const float* __restrict__ x, ushort* __restrict__ xh,
                              int total4, const int* __restrict__ dst,
                              ushort* __restrict__ rank, int* __restrict__ deg, int e) {
    int id = blockIdx.x * 256 + threadIdx.x;
    constexpr int C1 = IN_DIM * 64;
    constexpr int C2 = C1 + HID * 64;
    if (id < C1) {
        conv_B_elem(W1, B1p, id);
    } else if (id < C2) {
        conv_B_elem(W2, B2p, id - C1);
    } else if (id < C2 + total4) {
        int i = id - C2;
        float4 v = *(const float4*)(x + (size_t)i * 4);
        ushort4 o;
        o.x = __half_as_ushort(__float2half(v.x));
        o.y = __half_as_ushort(__float2half(v.y));
        o.z = __half_as_ushort(__float2half(v.z));
        o.w = __half_as_ushort(__float2half(v.w));
        *(ushort4*)(xh + (size_t)i * 4) = o;
    } else {
        int i = id - (C2 + total4);
        if (i < e) rank[i] = (ushort)atomicAdd(&deg[dst[i]], 1);
    }
}

// ---- scan phase 1: per-256-chunk scan + block total; also emits dinv ----
__global__ __launch_bounds__(256) void scan_partial(const int* __restrict__ deg,
                                                    int* __restrict__ escan,
                                                    int* __restrict__ blocksum,
                                                    float* __restrict__ dinv, int n) {
    __shared__ int lds[256];
    int t = threadIdx.x;
    int i = blockIdx.x * 256 + t;
    int v = (i < n) ? deg[i] : 0;
    if (i < n) dinv[i] = rsqrtf((float)v + 1.0f);
    lds[t] = v;
    __syncthreads();
    for (int off = 1; off < 256; off <<= 1) {
        int a = lds[t];
        int w = (t >= off) ? lds[t - off] : 0;
        __syncthreads();
        lds[t] = a + w;
        __syncthreads();
    }
    if (i < n) escan[i] = lds[t] - v;
    if (t == 255) blocksum[blockIdx.x] = lds[255];
}

// ---- fused scan-finish + scatter (replaces scan_rest + scatter_src) -------
// Every block redundantly scans the <=256 block sums in LDS (196x4B
// broadcast read -- free), emits its slice of rowptr, then grid-strides the
// edges computing the slot inline: escan[d] + bprefix[d>>8] + rank[i].
// No cross-block dependency, no atomics, one fewer graph node.
__global__ __launch_bounds__(256) void scanrest_scatter(
    const int* __restrict__ escan, const int* __restrict__ bsum, int nb,
    int* __restrict__ rowptr,
    const int* __restrict__ src, const int* __restrict__ dst,
    const ushort* __restrict__ rank, ushort* __restrict__ esrc,
    int n, int e)
{
    __shared__ int incl[256];
    __shared__ int excl[256];
    int t = threadIdx.x;
    int v = (t < nb) ? bsum[t] : 0;
    incl[t] = v;
    __syncthreads();
    for (int off = 1; off < 256; off <<= 1) {
        int a = incl[t];
        int w = (t >= off) ? incl[t - off] : 0;
        __syncthreads();
        incl[t] = a + w;
        __syncthreads();
    }
    excl[t] = incl[t] - v;
    __syncthreads();

    int gid0    = blockIdx.x * 256 + t;
    int gstride = gridDim.x * 256;
    for (int i = gid0; i < n; i += gstride)
        rowptr[i] = escan[i] + excl[i >> 8];
    if (blockIdx.x == 0 && t == 0) rowptr[n] = incl[nb - 1];
    for (int i = gid0; i < e; i += gstride) {
        int d = dst[i];
        esrc[escan[d] + excl[d >> 8] + (int)rank[i]] = (ushort)src[i];
    }
}

// ---------------- aggregation: one wave per node, fp16 gather, 8-deep ------
// Proven structure: clean uint2 gathers, ushort edge stream, dinv[s] looked
// up from the L2-resident table, dinv[d] factored out of the node sum.
template <int K>  // K halves per row: 128 or 256
__global__ __launch_bounds__(256) void aggregate_p(const ushort* __restrict__ h,
                                                   const int* __restrict__ rowptr,
                                                   const ushort* __restrict__ esrc,
                                                   const float* __restrict__ dinv,
                                                   ushort* __restrict__ Pp,
                                                   int n, int Mp) {
    constexpr int VH = K / 64;  // halves per lane: 2 or 4
    int wid  = (blockIdx.x * 256 + threadIdx.x) >> 6;
    int lane = threadIdx.x & 63;
    if (wid >= n) return;
    float di = dinv[wid];
    float acc[VH];
    {
        const ushort* row = h + (size_t)wid * K + lane * VH;
        if constexpr (VH == 4) {
            uint2 u = *(const uint2*)row;
            float2 fa = __half22float2(*(__half2*)&u.x);
            float2 fb = __half22float2(*(__half2*)&u.y);
            acc[0] = fa.x * di; acc[1] = fa.y * di; acc[2] = fb.x * di; acc[3] = fb.y * di;
        } else {
            uint u = *(const uint*)row;
            float2 fa = __half22float2(*(__half2*)&u);
            acc[0] = fa.x * di; acc[1] = fa.y * di;
        }
    }
    int beg = rowptr[wid], fin = rowptr[wid + 1];
    for (int b = beg; b < fin; b += 64) {
        int cnt = fin - b;
        if (cnt > 64) cnt = 64;
        int   sv = (lane < cnt) ? (int)esrc[b + lane] : 0;
        float wv = (lane < cnt) ? dinv[sv] : 0.f;
        int t = 0;
        for (; t + 8 <= cnt; t += 8) {
            float wr[8];
            if constexpr (VH == 4) {
                uint2 u[8];
#pragma unroll
                for (int k = 0; k < 8; k++) {
                    int s = __shfl(sv, t + k);
                    wr[k] = __shfl(wv, t + k);
                    u[k] = *(const uint2*)(h + (size_t)s * K + lane * VH);
                }
#pragma unroll
                for (int k = 0; k < 8; k++) {
                    float2 fa = __half22float2(*(__half2*)&u[k].x);
                    float2 fb = __half22float2(*(__half2*)&u[k].y);
                    acc[0] += fa.x * wr[k]; acc[1] += fa.y * wr[k];
                    acc[2] += fb.x * wr[k]; acc[3] += fb.y * wr[k];
                }
            } else {
                uint u[8];
#pragma unroll
                for (int k = 0; k < 8; k++) {
                    int s = __shfl(sv, t + k);
                    wr[k] = __shfl(wv, t + k);
                    u[k] = *(const uint*)(h + (size_t)s * K + lane * VH);
                }
#pragma unroll
                for (int k = 0; k < 8; k++) {
                    float2 fa = __half22float2(*(__half2*)&u[k]);
                    acc[0] += fa.x * wr[k]; acc[1] += fa.y * wr[k];
                }
            }
        }
        for (; t + 4 <= cnt; t += 4) {
            float wr[4];
            if constexpr (VH == 4) {
                uint2 u[4];
#pragma unroll
                for (int k = 0; k < 4; k++) {
                    int s = __shfl(sv, t + k);
                    wr[k] = __shfl(wv, t + k);
                    u[k] = *(const uint2*)(h + (size_t)s * K + lane * VH);
                }
#pragma unroll
                for (int k = 0; k < 4; k++) {
                    float2 fa = __half22float2(*(__half2*)&u[k].x);
                    float2 fb = __half22float2(*(__half2*)&u[k].y);
                    acc[0] += fa.x * wr[k]; acc[1] += fa.y * wr[k];
                    acc[2] += fb.x * wr[k]; acc[3] += fb.y * wr[k];
                }
            } else {
                uint u[4];
#pragma unroll
                for (int k = 0; k < 4; k++) {
                    int s = __shfl(sv, t + k);
                    wr[k] = __shfl(wv, t + k);
                    u[k] = *(const uint*)(h + (size_t)s * K + lane * VH);
                }
#pragma unroll
                for (int k = 0; k < 4; k++) {
                    float2 fa = __half22float2(*(__half2*)&u[k]);
                    acc[0] += fa.x * wr[k]; acc[1] += fa.y * wr[k];
                }
            }
        }
        for (; t < cnt; t++) {
            int   s = __shfl(sv, t);
            float w = __shfl(wv, t);
            const ushort* r = h + (size_t)s * K + lane * VH;
            if constexpr (VH == 4) {
                uint2 u = *(const uint2*)r;
                float2 fa = __half22float2(*(__half2*)&u.x);
                float2 fb = __half22float2(*(__half2*)&u.y);
                acc[0] += fa.x * w; acc[1] += fa.y * w;
                acc[2] += fb.x * w; acc[3] += fb.y * w;
            } else {
                uint u = *(const uint*)r;
                float2 fa = __half22float2(*(__half2*)&u);
                acc[0] += fa.x * w; acc[1] += fa.y * w;
            }
        }
    }
#pragma unroll
    for (int j = 0; j < VH; j++) acc[j] *= di;

    int kglob = lane * VH;
    int chunk = kglob >> 5;
    int inner = kglob & 31;
    size_t base = (size_t)chunk * Mp * 32 + (size_t)wid * 32 + inner;
    if constexpr (VH == 4) {
        __half2 p0 = __floats2half2_rn(acc[0], acc[1]);
        __half2 p1 = __floats2half2_rn(acc[2], acc[3]);
        *(uint2*)&Pp[base] = make_uint2(*(uint*)&p0, *(uint*)&p1);
    } else {
        __half2 p0 = __floats2half2_rn(acc[0], acc[1]);
        *(uint*)&Pp[base] = *(uint*)&p0;
    }
}

// ---------------- persistent-B fp16 MFMA GEMM ------------------------------
// MODE 1: C16[M,256] = fp16(relu(A@B + bias))
// MODE 2: out[M,2]  = relu(A@B + bias) @ Wl + bl
template <int K, int MODE>
__global__ __launch_bounds__(256, (MODE == 1) ? 2 : 1)
void gemm_p(const ushort* __restrict__ Ap, const ushort* __restrict__ Bp,
            const float* __restrict__ bias, ushort* __restrict__ C16,
            const float* __restrict__ Wl, const float* __restrict__ bl,
            float* __restrict__ out, int M, int Mp, int ntiles) {
    constexpr int NC   = K / 32;
    constexpr int NBUF = (MODE == 1) ? 2 : 1;
    __shared__ ushort Bsm[NC * 8192];          // whole B panel
    __shared__ ushort Asm[NBUF][NC * 1024];    // A tile(s) [chunk][row][32]

    int tid  = threadIdx.x;
    int w    = tid >> 6;
    int lane = tid & 63;
    int l15  = lane & 15;
    int quad = lane >> 4;

    for (int j = w; j < NC * 16; j += 4) {
        const ushort* g = Bp + (size_t)j * 512;
        __builtin_amdgcn_global_load_lds(
            (const __attribute__((address_space(1))) uint*)(g + (size_t)lane * 8),
            (__attribute__((address_space(3))) uint*)(Bsm + j * 512), 16, 0, 0);
    }

    auto stageA = [&](ushort* dl, int t) {
        int row0 = t * 32;
        for (int j = w; j < NC * 2; j += 4) {
            int c = j >> 1, sub = j & 1;
            const ushort* g = Ap + (size_t)c * Mp * 32 + (size_t)(row0 + sub * 16) * 32;
            __builtin_amdgcn_global_load_lds(
                (const __attribute__((address_space(1))) uint*)(g + (size_t)lane * 8),
                (__attribute__((address_space(3))) uint*)(dl + c * 1024 + sub * 512),
                16, 0, 0);
        }
    };

    float bj[4];
#pragma unroll
    for (int j = 0; j < 4; j++) bj[j] = bias[w * 64 + j * 16 + l15];
    float wl0[4], wl1[4];
    if constexpr (MODE == 2) {
#pragma unroll
        for (int j = 0; j < 4; j++) {
            int cj = w * 64 + j * 16 + l15;
            float2 wv = *(const float2*)(Wl + cj * 2);
            wl0[j] = wv.x; wl1[j] = wv.y;
        }
    }

    int cur = 0;
    if ((int)blockIdx.x < ntiles) stageA(Asm[0], blockIdx.x);

    for (int t = blockIdx.x; t < ntiles; t += gridDim.x) {
        __syncthreads();
        if constexpr (MODE == 1) {
            if (t + (int)gridDim.x < ntiles) stageA(Asm[cur ^ 1], t + gridDim.x);
        }
        f32x4 acc[2][4] = {};
#pragma unroll
        for (int c = 0; c < NC; c++) {
            f16x8 fa[2], fb[4];
#pragma unroll
            for (int i = 0; i < 2; i++) {
                int off = c * 1024 + (i * 16 + l15) * 32 + quad * 8;
                fa[i] = *(const f16x8*)&Asm[cur][off];
            }
#pragma unroll
            for (int j = 0; j < 4; j++) {
                int off = c * 8192 + (w * 64 + j * 16 + l15) * 32 + quad * 8;
                fb[j] = *(const f16x8*)&Bsm[off];
            }
#pragma unroll
            for (int i = 0; i < 2; i++)
#pragma unroll
                for (int j = 0; j < 4; j++)
                    acc[i][j] = __builtin_amdgcn_mfma_f32_16x16x32_f16(fa[i], fb[j], acc[i][j], 0, 0, 0);
        }

        int row0 = t * 32;
        if constexpr (MODE == 1) {
#pragma unroll
            for (int i = 0; i < 2; i++)
#pragma unroll
                for (int reg = 0; reg < 4; reg++) {
                    int r = row0 + i * 16 + quad * 4 + reg;
                    if (r < M) {
                        ushort* cp = C16 + (size_t)r * 256 + w * 64 + l15;
#pragma unroll
                        for (int j = 0; j < 4; j++) {
                            float v = fmaxf(acc[i][j][reg] + bj[j], 0.f);
                            cp[j * 16] = __half_as_ushort(__float2half(v));
                        }
                    }
                }
            cur ^= 1;
        } else {
            __shared__ float part[4][32][2];
#pragma unroll
            for (int i = 0; i < 2; i++)
#pragma unroll
                for (int reg = 0; reg < 4; reg++) {
                    float s0 = 0.f, s1 = 0.f;
#pragma unroll
                    for (int j = 0; j < 4; j++) {
                        float v = fmaxf(acc[i][j][reg] + bj[j], 0.f);
                        s0 += v * wl0[j];
                        s1 += v * wl1[j];
                    }
#pragma unroll
                    for (int off = 1; off < 16; off <<= 1) {
                        s0 += __shfl_xor(s0, off);
                        s1 += __shfl_xor(s1, off);
                    }
                    if (l15 == 0) {
                        int r = i * 16 + quad * 4 + reg;
                        part[w][r][0] = s0;
                        part[w][r][1] = s1;
                    }
                }
            __syncthreads();
            if (t + (int)gridDim.x < ntiles) stageA(Asm[0], t + gridDim.x);
            if (tid < 64) {
                int r = tid >> 1, o = tid & 1;
                int grr = row0 + r;
                if (grr < M) {
                    float s = part[0][r][o] + part[1][r][o] + part[2][r][o] + part[3][r][o] + bl[o];
                    out[(size_t)grr * 2 + o] = s;
                }
            }
        }
    }
}

// ---------------- launch ----------------

extern "C" void kernel_launch(void* const* d_in, const int* in_sizes, int n_in,
                              void* d_out, int out_size, void* d_ws, size_t ws_size,
                              hipStream_t stream) {
    const float* x  = (const float*)d_in[0];
    const int*   ei = (const int*)d_in[1];
    const float* W1 = (const float*)d_in[2];
    const float* b1 = (const float*)d_in[3];
    const float* W2 = (const float*)d_in[4];
    const float* b2 = (const float*)d_in[5];
    const float* Wl = (const float*)d_in[6];
    const float* bl = (const float*)d_in[7];
    float* out = (float*)d_out;

    int n = in_sizes[0] / IN_DIM;  // 50000
    int e = in_sizes[1] / 2;       // 600000
    const int* src = ei;
    const int* dst = ei + e;

    int gblocks = (n + 31) / 32;   // 32-row tiles
    int Mp = gblocks * 32;

    char* ws = (char*)d_ws;
    size_t off = 0;
    auto alloc = [&](size_t bytes) -> void* {
        void* p = ws + off;
        off += (bytes + 255) & ~(size_t)255;
        return p;
    };
    int*    deg     = (int*)alloc((size_t)n * 4);
    float*  dinv    = (float*)alloc((size_t)n * 4);
    int*    rowptr  = (int*)alloc((size_t)(n + 1) * 4);
    int*    escan   = (int*)alloc((size_t)n * 4);
    int*    bsum    = (int*)alloc(256 * 4);
    ushort* rank    = (ushort*)alloc((size_t)e * 2);
    ushort* esrc    = (ushort*)alloc((size_t)e * 2);
    ushort* xh      = (ushort*)alloc((size_t)n * IN_DIM * 2);
    ushort* h1      = (ushort*)alloc((size_t)n * HID * 2);
    ushort* A1p     = (ushort*)alloc((size_t)Mp * IN_DIM * 2);
    ushort* A2p     = (ushort*)alloc((size_t)Mp * HID * 2);
    ushort* B1p     = (ushort*)alloc((size_t)IN_DIM * 256 * 2);
    ushort* B2p     = (ushort*)alloc((size_t)HID * 256 * 2);

    int nb = (n + 255) / 256;   // 196 (<= 256 required by scanrest_scatter)
    int total4 = n * IN_DIM / 4;

    hipMemsetAsync(deg, 0, (size_t)n * 4, stream);

    int citems = IN_DIM * 64 + HID * 64 + total4 + e;
    convert_count<<<(citems + 255) / 256, 256, 0, stream>>>(W1, B1p, W2, B2p, x, xh,
                                                            total4, dst, rank, deg, e);

    scan_partial<<<nb, 256, 0, stream>>>(deg, escan, bsum, dinv, n);

    int sblocks = (e + 255) / 256;
    if (sblocks > 2048) sblocks = 2048;
    scanrest_scatter<<<sblocks, 256, 0, stream>>>(escan, bsum, nb, rowptr,
                                                  src, dst, rank, esrc, n, e);

    // layer 1: aggregate fp16 x -> A1 panel, persistent-B MFMA GEMM -> h1
    aggregate_p<IN_DIM><<<(n + 3) / 4, 256, 0, stream>>>(xh, rowptr, esrc, dinv,
                                                         A1p, n, Mp);
    gemm_p<IN_DIM, 1><<<512, 256, 0, stream>>>(A1p, B1p, b1, h1,
                                               nullptr, nullptr, nullptr,
                                               n, Mp, gblocks);

    // layer 2: aggregate fp16 h1 -> A2 panel, persistent-B GEMM + projection
    aggregate_p<HID><<<(n + 3) / 4, 256, 0, stream>>>(h1, rowptr, esrc, dinv,
                                                      A2p, n, Mp);
    gemm_p<HID, 2><<<256, 256, 0, stream>>>(A2p, B2p, b2, nullptr,
                                            Wl, bl, out, n, Mp, gblocks);
}